// Round 18
// baseline (182.813 us; speedup 1.0000x reference)
//
#include <hip/hip_runtime.h>
#include <math.h>

#define NN 100000
#define NE 1200000
#define CC 64
#define GG 256
#define RR 8
#define EPSF 1e-5f
#define BINS 782   // ceil(NN/128), bin = dst >> 7
#define BINP 1024  // padded (pow2)
#define EPB 4688   // edges per hist/phase1 block (256 blocks)

typedef __attribute__((ext_vector_type(8))) short bf16x8;
typedef __attribute__((ext_vector_type(4))) float f32x4;

__device__ inline unsigned short f2bf(float f) {
  unsigned u = __float_as_uint(f);
  return (unsigned short)((u + 0x7fffu + ((u >> 16) & 1u)) >> 16);  // RNE
}
__device__ inline float bf2f(unsigned short s) {
  return __uint_as_float(((unsigned)s) << 16);
}
__device__ inline float bfl(unsigned u) { return __uint_as_float(u << 16); }
__device__ inline float bfh(unsigned u) { return __uint_as_float(u & 0xffff0000u); }

// ---------- cvt: x (f32) -> xb (bf16), 8 elems/thread ----------
__global__ __launch_bounds__(256) void k_cvt(const float* __restrict__ x,
                                             unsigned short* __restrict__ xb) {
  int i = blockIdx.x * 256 + threadIdx.x;
  if (i >= NN * CC / 8) return;
  const float4* xp = (const float4*)(x + (size_t)i * 8);
  float4 a = xp[0], b = xp[1];
  uint4 o;
  o.x = (unsigned)f2bf(a.x) | ((unsigned)f2bf(a.y) << 16);
  o.y = (unsigned)f2bf(a.z) | ((unsigned)f2bf(a.w) << 16);
  o.z = (unsigned)f2bf(b.x) | ((unsigned)f2bf(b.y) << 16);
  o.w = (unsigned)f2bf(b.z) | ((unsigned)f2bf(b.w) << 16);
  *(uint4*)(xb + (size_t)i * 8) = o;
}

// ---------- cvtW: weights f32 -> bf16 ----------
__global__ __launch_bounds__(256) void k_cvtW(const float* __restrict__ Wl,
                                              const float* __restrict__ Wr,
                                              unsigned short* __restrict__ wbl,
                                              unsigned short* __restrict__ wbr) {
  int i = blockIdx.x * 256 + threadIdx.x;
  if (i < CC * CC) {
    wbl[i] = f2bf(Wl[i]);
    wbr[i] = f2bf(Wr[i]);
  }
}

// ---------- hist: global per-bin edge counts ----------
__global__ __launch_bounds__(256) void k_hist(const int* __restrict__ ei,
                                              int* __restrict__ bin_total) {
  __shared__ int hist[BINP];
  for (int t = threadIdx.x; t < BINP; t += 256) hist[t] = 0;
  __syncthreads();
  int start = blockIdx.x * EPB;
  int end = start + EPB < NE ? start + EPB : NE;
  for (int e = start + threadIdx.x; e < end; e += 256)
    atomicAdd(&hist[ei[NE + e] >> 7], 1);
  __syncthreads();
  for (int t = threadIdx.x; t < BINP; t += 256)
    if (hist[t]) atomicAdd(&bin_total[t], hist[t]);
}

// ---------- scan bins -> bin_base (exclusive) + cursor; rowptr[NN]=NE ----------
__global__ __launch_bounds__(1024) void k_scanbins(const int* __restrict__ bin_total,
                                                   int* __restrict__ bin_base,
                                                   int* __restrict__ cursor,
                                                   int* __restrict__ rowptr) {
  __shared__ int sh[BINP];
  int t = threadIdx.x;
  int v = t < BINS ? bin_total[t] : 0;
  sh[t] = v;
  __syncthreads();
  for (int d = 1; d < BINP; d <<= 1) {
    int val = sh[t];
    int add = (t >= d) ? sh[t - d] : 0;
    __syncthreads();
    sh[t] = val + add;
    __syncthreads();
  }
  int excl = sh[t] - v;
  if (t < BINS) {
    bin_base[t] = excl;
    cursor[t] = excl;
  }
  if (t == 0) {
    bin_base[BINS] = NE;
    rowptr[NN] = NE;
  }
}

// ---------- phase1: packed (src<<7)|(dst&127) into bin-contiguous buckets ----------
__global__ __launch_bounds__(256) void k_phase1(const int* __restrict__ ei,
                                                int* __restrict__ cursor,
                                                unsigned* __restrict__ ebuf) {
  __shared__ int hist[BINP];
  __shared__ int base[BINP];
  for (int t = threadIdx.x; t < BINP; t += 256) hist[t] = 0;
  __syncthreads();
  int start = blockIdx.x * EPB;
  int end = start + EPB < NE ? start + EPB : NE;
  for (int e = start + threadIdx.x; e < end; e += 256)
    atomicAdd(&hist[ei[NE + e] >> 7], 1);
  __syncthreads();
  for (int t = threadIdx.x; t < BINP; t += 256) {
    int c = hist[t];
    base[t] = c ? atomicAdd(&cursor[t], c) : 0;
  }
  __syncthreads();
  for (int t = threadIdx.x; t < BINP; t += 256) hist[t] = 0;
  __syncthreads();
  for (int e = start + threadIdx.x; e < end; e += 256) {
    int src = ei[e], dst = ei[NE + e];
    int b = dst >> 7;
    int off = atomicAdd(&hist[b], 1);
    ebuf[base[b] + off] = ((unsigned)src << 7) | (unsigned)(dst & 127);
  }
}

// ---------- fill2: per-bin CSR (rowptr + coalesced csr) ----------
__global__ __launch_bounds__(256) void k_fill2(const unsigned* __restrict__ ebuf,
                                               const int* __restrict__ bin_base,
                                               int* __restrict__ rowptr,
                                               int* __restrict__ csr) {
  __shared__ int cnt[128];
  __shared__ int sc[128];
  int tid = threadIdx.x;
  int b = blockIdx.x;
  int s = bin_base[b], e = bin_base[b + 1];
  if (tid < 128) cnt[tid] = 0;
  __syncthreads();
  for (int i = s + tid; i < e; i += 256) atomicAdd(&cnt[ebuf[i] & 127], 1);
  __syncthreads();
  if (tid < 128) sc[tid] = cnt[tid];
  __syncthreads();
  for (int d = 1; d < 128; d <<= 1) {
    int v = (tid < 128) ? sc[tid] : 0;
    int a = (tid >= d && tid < 128) ? sc[tid - d] : 0;
    __syncthreads();
    if (tid < 128) sc[tid] = v + a;
    __syncthreads();
  }
  if (tid < 128) {
    sc[tid] -= cnt[tid];  // exclusive
    int node = (b << 7) + tid;
    if (node < NN) rowptr[node] = s + sc[tid];
    cnt[tid] = 0;
  }
  __syncthreads();
  for (int i = s + tid; i < e; i += 256) {
    unsigned v = ebuf[i];
    int dl = v & 127;
    int off = atomicAdd(&cnt[dl], 1);
    csr[s + sc[dl] + off] = (int)(v >> 7);
  }
}

// ---------- gather: aggb[i] = bf16( mean of xb[src] ), wave per node ----------
// Vectorized: 16 lanes per edge (uint2 = 4 bf16 = 8B/lane), 4 edge-slots per
// wave, 8 edges in flight per loop iter. Butterfly (16,32) sums edge-slots.
__global__ __launch_bounds__(256) void k_gather(const unsigned short* __restrict__ xb,
                                                const int* __restrict__ csr,
                                                const int* __restrict__ rowptr,
                                                unsigned short* __restrict__ aggb) {
  int w = blockIdx.x * 4 + (threadIdx.x >> 6);
  int lane = threadIdx.x & 63;
  if (w >= NN) return;
  int s = rowptr[w], e = rowptr[w + 1];
  int sub = lane >> 4;        // edge slot 0..3
  int ch = (lane & 15) * 4;   // channel base
  float a0 = 0.f, a1 = 0.f, a2 = 0.f, a3 = 0.f;
  for (int j0 = s; j0 < e; j0 += 8) {
#pragma unroll
    for (int r = 0; r < 2; ++r) {
      int j = j0 + r * 4 + sub;
      int jc = j < e ? j : e - 1;
      int idx = csr[jc];
      uint2 v = *(const uint2*)(xb + (size_t)idx * CC + ch);
      if (j < e) {
        a0 += bfl(v.x); a1 += bfh(v.x);
        a2 += bfl(v.y); a3 += bfh(v.y);
      }
    }
  }
  a0 += __shfl_xor(a0, 16); a0 += __shfl_xor(a0, 32);
  a1 += __shfl_xor(a1, 16); a1 += __shfl_xor(a1, 32);
  a2 += __shfl_xor(a2, 16); a2 += __shfl_xor(a2, 32);
  a3 += __shfl_xor(a3, 16); a3 += __shfl_xor(a3, 32);
  if (sub == 0) {
    float inv = 1.0f / fmaxf((float)(e - s), 1.0f);
    uint2 o;
    o.x = (unsigned)f2bf(a0 * inv) | ((unsigned)f2bf(a1 * inv) << 16);
    o.y = (unsigned)f2bf(a2 * inv) | ((unsigned)f2bf(a3 * inv) << 16);
    *(uint2*)(aggb + (size_t)w * CC + ch) = o;
  }
}

// ---------- passA (MFMA): h = mean@Wl^T + bl + x@Wr^T ----------
__global__ __launch_bounds__(256) void k_passA(
    const unsigned short* __restrict__ xb, const unsigned short* __restrict__ aggb,
    const unsigned short* __restrict__ wbl, const unsigned short* __restrict__ wbr,
    const float* __restrict__ bl, float* __restrict__ h) {
  int lane = threadIdx.x & 63;
  int wave = threadIdx.x >> 6;
  int node0 = blockIdx.x * 64 + wave * 16;
  if (node0 >= NN) return;
  int lr = lane & 15;   // A row / B,C col
  int kg = lane >> 4;   // k-group

  bf16x8 WL[4][2], WR[4][2];
#pragma unroll
  for (int i = 0; i < 4; ++i)
#pragma unroll
    for (int t = 0; t < 2; ++t) {
      size_t off = (size_t)(i * 16 + lr) * CC + t * 32 + kg * 8;
      WL[i][t] = *(const bf16x8*)(wbl + off);
      WR[i][t] = *(const bf16x8*)(wbr + off);
    }

  int arow = node0 + lr;
  if (arow >= NN) arow = NN - 1;
  bf16x8 Aa[2], Ax[2];
#pragma unroll
  for (int t = 0; t < 2; ++t) {
    Aa[t] = *(const bf16x8*)(aggb + (size_t)arow * CC + t * 32 + kg * 8);
    Ax[t] = *(const bf16x8*)(xb + (size_t)arow * CC + t * 32 + kg * 8);
  }

  f32x4 acc[4];
#pragma unroll
  for (int i = 0; i < 4; ++i) {
    float b = bl[i * 16 + lr];  // bias depends on col only
    acc[i] = (f32x4){b, b, b, b};
  }
#pragma unroll
  for (int i = 0; i < 4; ++i) {
#pragma unroll
    for (int t = 0; t < 2; ++t) {
      acc[i] = __builtin_amdgcn_mfma_f32_16x16x32_bf16(Aa[t], WL[i][t], acc[i], 0, 0, 0);
      acc[i] = __builtin_amdgcn_mfma_f32_16x16x32_bf16(Ax[t], WR[i][t], acc[i], 0, 0, 0);
    }
  }

#pragma unroll
  for (int r = 0; r < 4; ++r) {
    int node = node0 + kg * 4 + r;
    if (node < NN) {
#pragma unroll
      for (int i = 0; i < 4; ++i)
        h[(size_t)node * CC + i * 16 + lr] = acc[i][r];
    }
  }
}

// ---------- stats: segmented per-graph sum(h), sum(h^2), count (batch sorted) ----------
__global__ __launch_bounds__(256) void k_stats(const float* __restrict__ h,
                                               const int* __restrict__ batch,
                                               float* __restrict__ sumH,
                                               float* __restrict__ sumH2,
                                               float* __restrict__ cntg) {
  int w = blockIdx.x * 4 + (threadIdx.x >> 6);
  int lane = threadIdx.x & 63;
  int i0 = w * 16;
  if (i0 >= NN) return;
  int iend = i0 + 16 < NN ? i0 + 16 : NN;
  int gcur = batch[i0];
  float aH = 0.0f, aH2 = 0.0f;
  int run = 0;
  for (int i = i0; i < iend; ++i) {
    int g = batch[i];  // wave-uniform
    if (g != gcur) {
      atomicAdd(&sumH[(size_t)gcur * CC + lane], aH);
      atomicAdd(&sumH2[(size_t)gcur * CC + lane], aH2);
      if (lane == 0) atomicAdd(&cntg[gcur], (float)run);
      aH = 0.0f; aH2 = 0.0f; run = 0;
      gcur = g;
    }
    float v = h[(size_t)i * CC + lane];
    aH += v;
    aH2 += v * v;
    run++;
  }
  atomicAdd(&sumH[(size_t)gcur * CC + lane], aH);
  atomicAdd(&sumH2[(size_t)gcur * CC + lane], aH2);
  if (lane == 0) atomicAdd(&cntg[gcur], (float)run);
}

// ---------- passC: normalize + gate + residual + relu (half-node threads) ----------
__global__ __launch_bounds__(256) void k_passC(
    const float* __restrict__ h, const float* __restrict__ x,
    const int* __restrict__ batch, const float* __restrict__ sumH,
    const float* __restrict__ sumH2, const float* __restrict__ cntg,
    const float* __restrict__ gw, const float* __restrict__ gb,
    const float* __restrict__ alpha, const float* __restrict__ a1w,
    const float* __restrict__ a1b, const float* __restrict__ a2w,
    const float* __restrict__ a2b, float* __restrict__ out) {
  __shared__ float A1[RR * CC];
  __shared__ float A2[CC * RR];
  __shared__ float A1B[RR];
  __shared__ float PRM[4 * CC];   // a2b | gw | gb | alpha
  for (int idx = threadIdx.x; idx < RR * CC; idx += 256) {
    A1[idx] = a1w[idx];
    A2[idx] = a2w[idx];
  }
  if (threadIdx.x < RR) A1B[threadIdx.x] = a1b[threadIdx.x];
  if (threadIdx.x < CC) {
    PRM[threadIdx.x] = a2b[threadIdx.x];
    PRM[CC + threadIdx.x] = gw[threadIdx.x];
    PRM[2 * CC + threadIdx.x] = gb[threadIdx.x];
    PRM[3 * CC + threadIdx.x] = alpha[threadIdx.x];
  }
  __syncthreads();

  int gid = blockIdx.x * 256 + threadIdx.x;
  int i = gid >> 1;
  if (i >= NN) return;
  int half = gid & 1;
  int base = half * 32;
  int g = batch[i];
  float rn = 1.0f / fmaxf(cntg[g], 1.0f);

  float xv[32];
  const float4* xp = (const float4*)(x + (size_t)i * CC + base);
#pragma unroll
  for (int q = 0; q < 8; ++q) {
    float4 b = xp[q];
    xv[4 * q] = b.x; xv[4 * q + 1] = b.y; xv[4 * q + 2] = b.z; xv[4 * q + 3] = b.w;
  }
  float p[RR];
#pragma unroll
  for (int r = 0; r < RR; ++r) {
    float acc = 0.0f;
    const float* a1p = A1 + r * CC + base;
#pragma unroll
    for (int k = 0; k < 32; ++k) acc = fmaf(xv[k], a1p[k], acc);
    acc += __shfl_xor(acc, 1);
    p[r] = fmaxf(acc + A1B[r], 0.0f);
  }
  const float4* hp = (const float4*)(h + (size_t)i * CC + base);
  const float4* sHp = (const float4*)(sumH + (size_t)g * CC + base);
  const float4* sH2p = (const float4*)(sumH2 + (size_t)g * CC + base);
  float4* op = (float4*)(out + (size_t)i * CC + base);
#pragma unroll 4
  for (int q = 0; q < 8; ++q) {
    float4 h4 = hp[q];
    float4 sH = sHp[q];
    float4 sH2 = sH2p[q];
    float hv[4] = {h4.x, h4.y, h4.z, h4.w};
    float sh[4] = {sH.x, sH.y, sH.z, sH.w};
    float sh2[4] = {sH2.x, sH2.y, sH2.z, sH2.w};
    float res[4];
#pragma unroll
    for (int u = 0; u < 4; ++u) {
      int c = base + q * 4 + u;
      float mu = sh[u] * rn;
      float t = PRM[3 * CC + c] * mu;
      float var = sh2[u] * rn - 2.0f * mu * t + t * t;
      float o = hv[u] - t;
      float y = fmaf(PRM[CC + c] * o, rsqrtf(var + EPSF), PRM[2 * CC + c]);
      float gacc = PRM[c];
#pragma unroll
      for (int r = 0; r < RR; ++r) gacc = fmaf(p[r], A2[c * RR + r], gacc);
      float gate = 1.0f / (1.0f + __expf(-gacc));
      res[u] = fmaxf(y + gate * xv[q * 4 + u], 0.0f);
    }
    op[q] = make_float4(res[0], res[1], res[2], res[3]);
  }
}

extern "C" void kernel_launch(void* const* d_in, const int* in_sizes, int n_in,
                              void* d_out, int out_size, void* d_ws, size_t ws_size,
                              hipStream_t stream) {
  const float* x        = (const float*)d_in[0];
  const int*   ei       = (const int*)d_in[1];
  const int*   batch    = (const int*)d_in[2];
  const float* Wl       = (const float*)d_in[3];
  const float* bl       = (const float*)d_in[4];
  const float* Wr       = (const float*)d_in[5];
  const float* gn_w     = (const float*)d_in[6];
  const float* gn_b     = (const float*)d_in[7];
  const float* gn_alpha = (const float*)d_in[8];
  const float* a1w      = (const float*)d_in[9];
  const float* a1b      = (const float*)d_in[10];
  const float* a2w      = (const float*)d_in[11];
  const float* a2b      = (const float*)d_in[12];
  float* out = (float*)d_out;

  // workspace layout (4B units)
  float*    h        = (float*)d_ws;                     // NN*CC
  unsigned* ebuf     = (unsigned*)(h + (size_t)NN * CC); // NE
  int*      csr      = (int*)(ebuf + NE);                // NE
  int*      rowptr   = csr + NE;                         // NN+1
  int*      bin_tot  = rowptr + NN + 1;                  // BINP  } zeroed
  float*    sumH     = (float*)(bin_tot + BINP);         // GG*CC } zeroed
  float*    sumH2    = sumH + GG * CC;                   // GG*CC } zeroed
  float*    cntg     = sumH2 + GG * CC;                  // GG    } zeroed
  int*      bin_base = (int*)(cntg + GG);                // BINS+1
  int*      cursor   = bin_base + BINS + 1;              // BINS
  unsigned short* wbl = (unsigned short*)(cursor + BINS);   // CC*CC bf16
  unsigned short* wbr = wbl + CC * CC;                      // CC*CC bf16
  // d_out doubles as bf16 scratch until passC overwrites it:
  unsigned short* xb   = (unsigned short*)d_out;         // NN*CC bf16
  unsigned short* aggb = xb + (size_t)NN * CC;           // NN*CC bf16

  size_t zbytes = ((size_t)BINP + 2 * GG * CC + GG) * sizeof(int);
  hipMemsetAsync((void*)bin_tot, 0, zbytes, stream);

  k_cvt     <<<(NN * CC / 8 + 255) / 256, 256, 0, stream>>>(x, xb);
  k_cvtW    <<<(CC * CC + 255) / 256, 256, 0, stream>>>(Wl, Wr, wbl, wbr);
  k_hist    <<<256, 256, 0, stream>>>(ei, bin_tot);
  k_scanbins<<<1, BINP, 0, stream>>>(bin_tot, bin_base, cursor, rowptr);
  k_phase1  <<<256, 256, 0, stream>>>(ei, cursor, ebuf);
  k_fill2   <<<BINS, 256, 0, stream>>>(ebuf, bin_base, rowptr, csr);
  k_gather  <<<(NN + 3) / 4, 256, 0, stream>>>(xb, csr, rowptr, aggb);
  k_passA   <<<(NN + 63) / 64, 256, 0, stream>>>(xb, aggb, wbl, wbr, bl, h);
  k_stats   <<<((NN + 15) / 16 + 3) / 4, 256, 0, stream>>>(h, batch, sumH, sumH2, cntg);
  k_passC   <<<(NN * 2 + 255) / 256, 256, 0, stream>>>(h, x, batch, sumH, sumH2, cntg,
                                                       gn_w, gn_b, gn_alpha,
                                                       a1w, a1b, a2w, a2b, out);
}

// Round 19
// 173.222 us; speedup vs baseline: 1.0554x; 1.0554x over previous
//
#include <hip/hip_runtime.h>
#include <math.h>

#define NN 100000
#define NE 1200000
#define CC 64
#define GG 256
#define RR 8
#define EPSF 1e-5f
#define BINS 782   // ceil(NN/128), bin = dst >> 7
#define BINP 1024  // padded (pow2)
#define EPB 4688   // edges per hist/phase1 block (256 blocks)

typedef __attribute__((ext_vector_type(8))) short bf16x8;
typedef __attribute__((ext_vector_type(4))) float f32x4;

__device__ inline unsigned short f2bf(float f) {
  unsigned u = __float_as_uint(f);
  return (unsigned short)((u + 0x7fffu + ((u >> 16) & 1u)) >> 16);  // RNE
}
__device__ inline float bf2f(unsigned short s) {
  return __uint_as_float(((unsigned)s) << 16);
}

// ---------- cvt: x (f32) -> xb (bf16), 8 elems/thread ----------
__global__ __launch_bounds__(256) void k_cvt(const float* __restrict__ x,
                                             unsigned short* __restrict__ xb) {
  int i = blockIdx.x * 256 + threadIdx.x;
  if (i >= NN * CC / 8) return;
  const float4* xp = (const float4*)(x + (size_t)i * 8);
  float4 a = xp[0], b = xp[1];
  uint4 o;
  o.x = (unsigned)f2bf(a.x) | ((unsigned)f2bf(a.y) << 16);
  o.y = (unsigned)f2bf(a.z) | ((unsigned)f2bf(a.w) << 16);
  o.z = (unsigned)f2bf(b.x) | ((unsigned)f2bf(b.y) << 16);
  o.w = (unsigned)f2bf(b.z) | ((unsigned)f2bf(b.w) << 16);
  *(uint4*)(xb + (size_t)i * 8) = o;
}

// ---------- cvtW: weights f32 -> bf16 ----------
__global__ __launch_bounds__(256) void k_cvtW(const float* __restrict__ Wl,
                                              const float* __restrict__ Wr,
                                              unsigned short* __restrict__ wbl,
                                              unsigned short* __restrict__ wbr) {
  int i = blockIdx.x * 256 + threadIdx.x;
  if (i < CC * CC) {
    wbl[i] = f2bf(Wl[i]);
    wbr[i] = f2bf(Wr[i]);
  }
}

// ---------- hist: global per-bin edge counts ----------
__global__ __launch_bounds__(256) void k_hist(const int* __restrict__ ei,
                                              int* __restrict__ bin_total) {
  __shared__ int hist[BINP];
  for (int t = threadIdx.x; t < BINP; t += 256) hist[t] = 0;
  __syncthreads();
  int start = blockIdx.x * EPB;
  int end = start + EPB < NE ? start + EPB : NE;
  for (int e = start + threadIdx.x; e < end; e += 256)
    atomicAdd(&hist[ei[NE + e] >> 7], 1);
  __syncthreads();
  for (int t = threadIdx.x; t < BINP; t += 256)
    if (hist[t]) atomicAdd(&bin_total[t], hist[t]);
}

// ---------- scan bins -> bin_base (exclusive) + cursor; rowptr[NN]=NE ----------
__global__ __launch_bounds__(1024) void k_scanbins(const int* __restrict__ bin_total,
                                                   int* __restrict__ bin_base,
                                                   int* __restrict__ cursor,
                                                   int* __restrict__ rowptr) {
  __shared__ int sh[BINP];
  int t = threadIdx.x;
  int v = t < BINS ? bin_total[t] : 0;
  sh[t] = v;
  __syncthreads();
  for (int d = 1; d < BINP; d <<= 1) {
    int val = sh[t];
    int add = (t >= d) ? sh[t - d] : 0;
    __syncthreads();
    sh[t] = val + add;
    __syncthreads();
  }
  int excl = sh[t] - v;
  if (t < BINS) {
    bin_base[t] = excl;
    cursor[t] = excl;
  }
  if (t == 0) {
    bin_base[BINS] = NE;
    rowptr[NN] = NE;
  }
}

// ---------- phase1: packed (src<<7)|(dst&127) into bin-contiguous buckets ----------
__global__ __launch_bounds__(256) void k_phase1(const int* __restrict__ ei,
                                                int* __restrict__ cursor,
                                                unsigned* __restrict__ ebuf) {
  __shared__ int hist[BINP];
  __shared__ int base[BINP];
  for (int t = threadIdx.x; t < BINP; t += 256) hist[t] = 0;
  __syncthreads();
  int start = blockIdx.x * EPB;
  int end = start + EPB < NE ? start + EPB : NE;
  for (int e = start + threadIdx.x; e < end; e += 256)
    atomicAdd(&hist[ei[NE + e] >> 7], 1);
  __syncthreads();
  for (int t = threadIdx.x; t < BINP; t += 256) {
    int c = hist[t];
    base[t] = c ? atomicAdd(&cursor[t], c) : 0;
  }
  __syncthreads();
  for (int t = threadIdx.x; t < BINP; t += 256) hist[t] = 0;
  __syncthreads();
  for (int e = start + threadIdx.x; e < end; e += 256) {
    int src = ei[e], dst = ei[NE + e];
    int b = dst >> 7;
    int off = atomicAdd(&hist[b], 1);
    ebuf[base[b] + off] = ((unsigned)src << 7) | (unsigned)(dst & 127);
  }
}

// ---------- fill2: per-bin CSR (rowptr + coalesced csr of BYTE offsets) ----------
__global__ __launch_bounds__(256) void k_fill2(const unsigned* __restrict__ ebuf,
                                               const int* __restrict__ bin_base,
                                               int* __restrict__ rowptr,
                                               int* __restrict__ csr) {
  __shared__ int cnt[128];
  __shared__ int sc[128];
  int tid = threadIdx.x;
  int b = blockIdx.x;
  int s = bin_base[b], e = bin_base[b + 1];
  if (tid < 128) cnt[tid] = 0;
  __syncthreads();
  for (int i = s + tid; i < e; i += 256) atomicAdd(&cnt[ebuf[i] & 127], 1);
  __syncthreads();
  if (tid < 128) sc[tid] = cnt[tid];
  __syncthreads();
  for (int d = 1; d < 128; d <<= 1) {
    int v = (tid < 128) ? sc[tid] : 0;
    int a = (tid >= d && tid < 128) ? sc[tid - d] : 0;
    __syncthreads();
    if (tid < 128) sc[tid] = v + a;
    __syncthreads();
  }
  if (tid < 128) {
    sc[tid] -= cnt[tid];  // exclusive
    int node = (b << 7) + tid;
    if (node < NN) rowptr[node] = s + sc[tid];
    cnt[tid] = 0;
  }
  __syncthreads();
  for (int i = s + tid; i < e; i += 256) {
    unsigned v = ebuf[i];
    int dl = v & 127;
    int off = atomicAdd(&cnt[dl], 1);
    csr[s + sc[dl] + off] = (int)(v >> 7) * (CC * 2);  // pre-scaled byte offset
  }
}

// ---------- gather: aggb[i] = bf16( mean of xb[src] ), wave per node ----------
// r17-proven structure: 64 lanes = channels, 8 independent scalar row-loads
// in flight (wave-uniform csr offsets via s_load; csr holds BYTE offsets so
// per-lane addressing is base + off + lane*2, no 64-bit multiply).
__global__ __launch_bounds__(256) void k_gather(const unsigned short* __restrict__ xb,
                                                const int* __restrict__ csr,
                                                const int* __restrict__ rowptr,
                                                unsigned short* __restrict__ aggb) {
  int w = blockIdx.x * 4 + (threadIdx.x >> 6);
  int lane = threadIdx.x & 63;
  if (w >= NN) return;
  int s = rowptr[w], e = rowptr[w + 1];
  const char* xbase = (const char*)xb + lane * 2;
  float acc = 0.0f;
  for (int j0 = s; j0 < e; j0 += 8) {
    int off[8];
#pragma unroll
    for (int u = 0; u < 8; ++u) {
      int j = j0 + u;
      off[u] = csr[j < e ? j : e - 1];  // wave-uniform byte offset -> s_load
    }
    float v[8];
#pragma unroll
    for (int u = 0; u < 8; ++u)
      v[u] = bf2f(*(const unsigned short*)(xbase + off[u]));
#pragma unroll
    for (int u = 0; u < 8; ++u) acc += (j0 + u < e) ? v[u] : 0.0f;
  }
  float inv = 1.0f / fmaxf((float)(e - s), 1.0f);
  aggb[(size_t)w * CC + lane] = f2bf(acc * inv);
}

// ---------- passA (MFMA): h = mean@Wl^T + bl + x@Wr^T ----------
__global__ __launch_bounds__(256) void k_passA(
    const unsigned short* __restrict__ xb, const unsigned short* __restrict__ aggb,
    const unsigned short* __restrict__ wbl, const unsigned short* __restrict__ wbr,
    const float* __restrict__ bl, float* __restrict__ h) {
  int lane = threadIdx.x & 63;
  int wave = threadIdx.x >> 6;
  int node0 = blockIdx.x * 64 + wave * 16;
  if (node0 >= NN) return;
  int lr = lane & 15;   // A row / B,C col
  int kg = lane >> 4;   // k-group

  bf16x8 WL[4][2], WR[4][2];
#pragma unroll
  for (int i = 0; i < 4; ++i)
#pragma unroll
    for (int t = 0; t < 2; ++t) {
      size_t off = (size_t)(i * 16 + lr) * CC + t * 32 + kg * 8;
      WL[i][t] = *(const bf16x8*)(wbl + off);
      WR[i][t] = *(const bf16x8*)(wbr + off);
    }

  int arow = node0 + lr;
  if (arow >= NN) arow = NN - 1;
  bf16x8 Aa[2], Ax[2];
#pragma unroll
  for (int t = 0; t < 2; ++t) {
    Aa[t] = *(const bf16x8*)(aggb + (size_t)arow * CC + t * 32 + kg * 8);
    Ax[t] = *(const bf16x8*)(xb + (size_t)arow * CC + t * 32 + kg * 8);
  }

  f32x4 acc[4];
#pragma unroll
  for (int i = 0; i < 4; ++i) {
    float b = bl[i * 16 + lr];  // bias depends on col only
    acc[i] = (f32x4){b, b, b, b};
  }
#pragma unroll
  for (int i = 0; i < 4; ++i) {
#pragma unroll
    for (int t = 0; t < 2; ++t) {
      acc[i] = __builtin_amdgcn_mfma_f32_16x16x32_bf16(Aa[t], WL[i][t], acc[i], 0, 0, 0);
      acc[i] = __builtin_amdgcn_mfma_f32_16x16x32_bf16(Ax[t], WR[i][t], acc[i], 0, 0, 0);
    }
  }

#pragma unroll
  for (int r = 0; r < 4; ++r) {
    int node = node0 + kg * 4 + r;
    if (node < NN) {
#pragma unroll
      for (int i = 0; i < 4; ++i)
        h[(size_t)node * CC + i * 16 + lr] = acc[i][r];
    }
  }
}

// ---------- stats: segmented per-graph sum(h), sum(h^2), count (batch sorted) ----------
__global__ __launch_bounds__(256) void k_stats(const float* __restrict__ h,
                                               const int* __restrict__ batch,
                                               float* __restrict__ sumH,
                                               float* __restrict__ sumH2,
                                               float* __restrict__ cntg) {
  int w = blockIdx.x * 4 + (threadIdx.x >> 6);
  int lane = threadIdx.x & 63;
  int i0 = w * 16;
  if (i0 >= NN) return;
  int iend = i0 + 16 < NN ? i0 + 16 : NN;
  int gcur = batch[i0];
  float aH = 0.0f, aH2 = 0.0f;
  int run = 0;
  for (int i = i0; i < iend; ++i) {
    int g = batch[i];  // wave-uniform
    if (g != gcur) {
      atomicAdd(&sumH[(size_t)gcur * CC + lane], aH);
      atomicAdd(&sumH2[(size_t)gcur * CC + lane], aH2);
      if (lane == 0) atomicAdd(&cntg[gcur], (float)run);
      aH = 0.0f; aH2 = 0.0f; run = 0;
      gcur = g;
    }
    float v = h[(size_t)i * CC + lane];
    aH += v;
    aH2 += v * v;
    run++;
  }
  atomicAdd(&sumH[(size_t)gcur * CC + lane], aH);
  atomicAdd(&sumH2[(size_t)gcur * CC + lane], aH2);
  if (lane == 0) atomicAdd(&cntg[gcur], (float)run);
}

// ---------- passC: normalize + gate + residual + relu (half-node threads) ----------
__global__ __launch_bounds__(256) void k_passC(
    const float* __restrict__ h, const float* __restrict__ x,
    const int* __restrict__ batch, const float* __restrict__ sumH,
    const float* __restrict__ sumH2, const float* __restrict__ cntg,
    const float* __restrict__ gw, const float* __restrict__ gb,
    const float* __restrict__ alpha, const float* __restrict__ a1w,
    const float* __restrict__ a1b, const float* __restrict__ a2w,
    const float* __restrict__ a2b, float* __restrict__ out) {
  __shared__ float A1[RR * CC];
  __shared__ float A2[CC * RR];
  __shared__ float A1B[RR];
  __shared__ float PRM[4 * CC];   // a2b | gw | gb | alpha
  for (int idx = threadIdx.x; idx < RR * CC; idx += 256) {
    A1[idx] = a1w[idx];
    A2[idx] = a2w[idx];
  }
  if (threadIdx.x < RR) A1B[threadIdx.x] = a1b[threadIdx.x];
  if (threadIdx.x < CC) {
    PRM[threadIdx.x] = a2b[threadIdx.x];
    PRM[CC + threadIdx.x] = gw[threadIdx.x];
    PRM[2 * CC + threadIdx.x] = gb[threadIdx.x];
    PRM[3 * CC + threadIdx.x] = alpha[threadIdx.x];
  }
  __syncthreads();

  int gid = blockIdx.x * 256 + threadIdx.x;
  int i = gid >> 1;
  if (i >= NN) return;
  int half = gid & 1;
  int base = half * 32;
  int g = batch[i];
  float rn = 1.0f / fmaxf(cntg[g], 1.0f);

  float xv[32];
  const float4* xp = (const float4*)(x + (size_t)i * CC + base);
#pragma unroll
  for (int q = 0; q < 8; ++q) {
    float4 b = xp[q];
    xv[4 * q] = b.x; xv[4 * q + 1] = b.y; xv[4 * q + 2] = b.z; xv[4 * q + 3] = b.w;
  }
  float p[RR];
#pragma unroll
  for (int r = 0; r < RR; ++r) {
    float acc = 0.0f;
    const float* a1p = A1 + r * CC + base;
#pragma unroll
    for (int k = 0; k < 32; ++k) acc = fmaf(xv[k], a1p[k], acc);
    acc += __shfl_xor(acc, 1);
    p[r] = fmaxf(acc + A1B[r], 0.0f);
  }
  const float4* hp = (const float4*)(h + (size_t)i * CC + base);
  const float4* sHp = (const float4*)(sumH + (size_t)g * CC + base);
  const float4* sH2p = (const float4*)(sumH2 + (size_t)g * CC + base);
  float4* op = (float4*)(out + (size_t)i * CC + base);
#pragma unroll 4
  for (int q = 0; q < 8; ++q) {
    float4 h4 = hp[q];
    float4 sH = sHp[q];
    float4 sH2 = sH2p[q];
    float hv[4] = {h4.x, h4.y, h4.z, h4.w};
    float sh[4] = {sH.x, sH.y, sH.z, sH.w};
    float sh2[4] = {sH2.x, sH2.y, sH2.z, sH2.w};
    float res[4];
#pragma unroll
    for (int u = 0; u < 4; ++u) {
      int c = base + q * 4 + u;
      float mu = sh[u] * rn;
      float t = PRM[3 * CC + c] * mu;
      float var = sh2[u] * rn - 2.0f * mu * t + t * t;
      float o = hv[u] - t;
      float y = fmaf(PRM[CC + c] * o, rsqrtf(var + EPSF), PRM[2 * CC + c]);
      float gacc = PRM[c];
#pragma unroll
      for (int r = 0; r < RR; ++r) gacc = fmaf(p[r], A2[c * RR + r], gacc);
      float gate = 1.0f / (1.0f + __expf(-gacc));
      res[u] = fmaxf(y + gate * xv[q * 4 + u], 0.0f);
    }
    op[q] = make_float4(res[0], res[1], res[2], res[3]);
  }
}

extern "C" void kernel_launch(void* const* d_in, const int* in_sizes, int n_in,
                              void* d_out, int out_size, void* d_ws, size_t ws_size,
                              hipStream_t stream) {
  const float* x        = (const float*)d_in[0];
  const int*   ei       = (const int*)d_in[1];
  const int*   batch    = (const int*)d_in[2];
  const float* Wl       = (const float*)d_in[3];
  const float* bl       = (const float*)d_in[4];
  const float* Wr       = (const float*)d_in[5];
  const float* gn_w     = (const float*)d_in[6];
  const float* gn_b     = (const float*)d_in[7];
  const float* gn_alpha = (const float*)d_in[8];
  const float* a1w      = (const float*)d_in[9];
  const float* a1b      = (const float*)d_in[10];
  const float* a2w      = (const float*)d_in[11];
  const float* a2b      = (const float*)d_in[12];
  float* out = (float*)d_out;

  // workspace layout (4B units)
  float*    h        = (float*)d_ws;                     // NN*CC
  unsigned* ebuf     = (unsigned*)(h + (size_t)NN * CC); // NE
  int*      csr      = (int*)(ebuf + NE);                // NE
  int*      rowptr   = csr + NE;                         // NN+1
  int*      bin_tot  = rowptr + NN + 1;                  // BINP  } zeroed
  float*    sumH     = (float*)(bin_tot + BINP);         // GG*CC } zeroed
  float*    sumH2    = sumH + GG * CC;                   // GG*CC } zeroed
  float*    cntg     = sumH2 + GG * CC;                  // GG    } zeroed
  int*      bin_base = (int*)(cntg + GG);                // BINS+1
  int*      cursor   = bin_base + BINS + 1;              // BINS
  unsigned short* wbl = (unsigned short*)(cursor + BINS);   // CC*CC bf16
  unsigned short* wbr = wbl + CC * CC;                      // CC*CC bf16
  // d_out doubles as bf16 scratch until passC overwrites it:
  unsigned short* xb   = (unsigned short*)d_out;         // NN*CC bf16
  unsigned short* aggb = xb + (size_t)NN * CC;           // NN*CC bf16

  size_t zbytes = ((size_t)BINP + 2 * GG * CC + GG) * sizeof(int);
  hipMemsetAsync((void*)bin_tot, 0, zbytes, stream);

  k_cvt     <<<(NN * CC / 8 + 255) / 256, 256, 0, stream>>>(x, xb);
  k_cvtW    <<<(CC * CC + 255) / 256, 256, 0, stream>>>(Wl, Wr, wbl, wbr);
  k_hist    <<<256, 256, 0, stream>>>(ei, bin_tot);
  k_scanbins<<<1, BINP, 0, stream>>>(bin_tot, bin_base, cursor, rowptr);
  k_phase1  <<<256, 256, 0, stream>>>(ei, cursor, ebuf);
  k_fill2   <<<BINS, 256, 0, stream>>>(ebuf, bin_base, rowptr, csr);
  k_gather  <<<(NN + 3) / 4, 256, 0, stream>>>(xb, csr, rowptr, aggb);
  k_passA   <<<(NN + 63) / 64, 256, 0, stream>>>(xb, aggb, wbl, wbr, bl, h);
  k_stats   <<<((NN + 15) / 16 + 3) / 4, 256, 0, stream>>>(h, batch, sumH, sumH2, cntg);
  k_passC   <<<(NN * 2 + 255) / 256, 256, 0, stream>>>(h, x, batch, sumH, sumH2, cntg,
                                                       gn_w, gn_b, gn_alpha,
                                                       a1w, a1b, a2w, a2b, out);
}